// Round 7
// baseline (242.092 us; speedup 1.0000x reference)
//
#include <hip/hip_runtime.h>
#include <stdint.h>

#define NSEG 50
#define HID 128
#define KDIM 2144      // 64 + 2016 + 64
#define KD2 2176       // padded to 34*64 for BK=64
#define KD2B 4352      // row bytes fp16
#define NROW 20000     // 400 * 50
#define NROW_PAD 20096 // 314 * 64
#define GATES 512
#define NSEQ 400

typedef __attribute__((ext_vector_type(8))) _Float16 f16x8;
typedef __attribute__((ext_vector_type(4))) float f32x4;
typedef __attribute__((ext_vector_type(4))) uint32_t u32x4;

#define GLB_SPACE __attribute__((address_space(1)))
#define LDS_SPACE __attribute__((address_space(3)))

__device__ __forceinline__ void g2lds16(const void* g, void* l) {
    __builtin_amdgcn_global_load_lds((const GLB_SPACE uint32_t*)g,
                                     (LDS_SPACE uint32_t*)l, 16, 0, 0);
}

// ---------------- prep: cast W_ih (K-padded) and W_hh to fp16, sum biases ---------------
__global__ __launch_bounds__(256) void prep_kernel(const float* __restrict__ Wih,
                                                   const float* __restrict__ Whh,
                                                   const float* __restrict__ bih,
                                                   const float* __restrict__ bhh,
                                                   _Float16* __restrict__ wh,
                                                   _Float16* __restrict__ whh16,
                                                   float* __restrict__ bias) {
    int idx = blockIdx.x * 256 + threadIdx.x;
    const int nwih = 512 * KD2;
    const int nwhh = 512 * HID;
    if (idx < nwih) {
        int row = idx / KD2;
        int k = idx - row * KD2;
        wh[idx] = (k < KDIM) ? (_Float16)Wih[row * KDIM + k] : (_Float16)0.0f;
    } else if (idx < nwih + nwhh) {
        int q = idx - nwih;
        whh16[q] = (_Float16)Whh[q];
    } else if (idx < nwih + nwhh + 512) {
        int g = idx - nwih - nwhh;
        bias[g] = bih[g] + bhh[g];
    }
}

// ---------------- features: one block per (b, s); rank-2 levy area ----------------------
// dev_0 == 0, so S2 = (p1-p0)x(p2-p1) + (p2-p0)x(p3-p2)
__global__ __launch_bounds__(256) void feat_kernel(const float* __restrict__ x,
                                                   _Float16* __restrict__ feat) {
    int bid = blockIdx.x;          // 0..799
    int b = bid / NSEG;
    int s = bid - b * NSEG;
    int tid = threadIdx.x;

    __shared__ float pbuf[64 * 100];        // p[c][t*25+v], t in 0..3, v in 0..24
    __shared__ float2 uu[25 * 64];          // (u1,u2) per (v,c)
    __shared__ float2 vvb[25 * 64];         // (v1,v2) per (v,c)

    // load: x[b][c][4s+t][v] -> 100 contiguous floats per c
    for (int i = tid; i < 6400; i += 256) {
        int c = i / 100;
        int r = i - c * 100;
        pbuf[c * 100 + r] = x[(((size_t)b * 64 + c) * 200 + 4 * s) * 25 + r];
    }
    // zero the K-pad columns for this block's 25 rows
    if (tid < 800) {
        int v = tid >> 5;
        int k = 2144 + (tid & 31);
        size_t m = ((size_t)(b * 25 + v)) * NSEG + s;
        feat[m * KD2 + k] = (_Float16)0.0f;
    }
    __syncthreads();

    // derived vectors + lvl1/start features
    for (int i = tid; i < 1600; i += 256) {
        int v = i >> 6;
        int c = i & 63;
        float p0 = pbuf[c * 100 + v];
        float p1 = pbuf[c * 100 + 25 + v];
        float p2 = pbuf[c * 100 + 50 + v];
        float p3 = pbuf[c * 100 + 75 + v];
        uu[v * 64 + c] = make_float2(p1 - p0, p2 - p0);
        vvb[v * 64 + c] = make_float2(p2 - p1, p3 - p2);
        size_t m = ((size_t)(b * 25 + v)) * NSEG + s;
        feat[m * KD2 + c] = (_Float16)(p3 - p0);             // lvl1
        feat[m * KD2 + 2080 + c] = (_Float16)p0;             // start
    }
    __syncthreads();

    // levy: 2016 upper-triangle pairs, threads over k (coalesced 2B stores), v inner
    for (int ch = 0; ch < 8; ch++) {
        int pidx = ch * 256 + tid;
        if (pidx < 2016) {
            float disc = 16129.0f - 8.0f * (float)pidx;      // (127-2i)^2 at row starts
            int i = (int)((127.0f - sqrtf(disc)) * 0.5f);
            int off = 63 * i - (i * (i - 1)) / 2;
            while (off > pidx) { i--; off = 63 * i - (i * (i - 1)) / 2; }
            while (63 * (i + 1) - ((i + 1) * i) / 2 <= pidx) { i++; off = 63 * i - (i * (i - 1)) / 2; }
            int j = pidx - off + i + 1;
            int k = 64 + pidx;
            for (int v = 0; v < 25; v++) {
                float2 ui = uu[v * 64 + i], uj = uu[v * 64 + j];
                float2 vi = vvb[v * 64 + i], vj = vvb[v * 64 + j];
                float val = 0.5f * (ui.x * vj.x - uj.x * vi.x + ui.y * vj.y - uj.y * vi.y);
                size_t m = ((size_t)(b * 25 + v)) * NSEG + s;
                feat[m * KD2 + k] = (_Float16)val;
            }
        }
    }
}

// ---------------- GEMM: xproj2[s][q][gate] = feat @ W_ih^T + bias (fp16 out) ------------
// BM=64, BN=128, BK=64; grid 1256 = 314*4 (no dead blocks, ~4.9 blocks/CU resident,
// LDS 24KB allows 6). bid&3 = nb: the 4 n-siblings of an m-tile are dispatch-adjacent
// -> A-tile LLC-deduped. 4 waves, wave tile 32x64 (16 MFMA / wave / kt).
__global__ __launch_bounds__(256, 4) void gemm_kernel(const _Float16* __restrict__ feat,
                                                      const _Float16* __restrict__ wh,
                                                      const float* __restrict__ bias,
                                                      _Float16* __restrict__ xproj2) {
    int bid = blockIdx.x;
    int nb = bid & 3;
    int mt = bid >> 2;             // 0..313
    int m0 = mt * 64;
    int n0 = nb * 128;
    int tid = threadIdx.x;
    int wave = tid >> 6;
    int lane = tid & 63;
    int quad = lane >> 4;
    int l15 = lane & 15;
    int wm = (wave & 1) * 32;
    int wn = (wave >> 1) * 64;

    int r8 = lane >> 3;                        // row within 8-row staging group
    int gcol = ((lane & 7) * 16) ^ (r8 * 16);  // XOR-swizzled source byte-col

    __shared__ __align__(16) _Float16 smem[12288];   // 24 KB K-loop; epilogue 64x132 = 16.9 KB
    char* As = (char*)smem;                    // 64 rows x 128 B
    char* Bs = (char*)smem + 64 * 128;         // 128 rows x 128 B

    const f32x4 z4 = {0.f, 0.f, 0.f, 0.f};
    f32x4 acc[2][4];
    for (int i = 0; i < 2; i++)
        for (int j = 0; j < 4; j++) acc[i][j] = z4;

    const char* featB = (const char*)feat;
    const char* whB = (const char*)wh;

    for (int kt = 0; kt < 34; kt++) {
        size_t kb = (size_t)kt * 128;
        __syncthreads();
        for (int it = 0; it < 2; it++) {
            int rb = it * 32 + wave * 8;
            g2lds16(featB + (size_t)(m0 + rb + r8) * KD2B + kb + gcol, As + rb * 128);
        }
        for (int it = 0; it < 4; it++) {
            int rb = it * 32 + wave * 8;
            g2lds16(whB + (size_t)(n0 + rb + r8) * KD2B + kb + gcol, Bs + rb * 128);
        }
        __syncthreads();

        for (int ks = 0; ks < 2; ks++) {
            int off = ((ks * 64) | (quad * 16)) ^ ((l15 & 7) * 16);
            f16x8 af[2], bf[4];
            for (int tt = 0; tt < 2; tt++)
                af[tt] = *(const f16x8*)(As + (wm + tt * 16 + l15) * 128 + off);
            for (int tt = 0; tt < 4; tt++)
                bf[tt] = *(const f16x8*)(Bs + (wn + tt * 16 + l15) * 128 + off);
            for (int mtl = 0; mtl < 2; mtl++)
                for (int ntl = 0; ntl < 4; ntl++)
                    acc[mtl][ntl] = __builtin_amdgcn_mfma_f32_16x16x32_f16(af[mtl], bf[ntl], acc[mtl][ntl], 0, 0, 0);
        }
    }

    // epilogue: stage fp16 tile in LDS (row stride 132 halfwords -> conflict-free writes)
    __syncthreads();
    for (int ntl = 0; ntl < 4; ntl++) {
        int nl = wn + ntl * 16 + l15;
        float bv = bias[n0 + nl];
        for (int mtl = 0; mtl < 2; mtl++)
            for (int r = 0; r < 4; r++) {
                int ml = wm + mtl * 16 + quad * 4 + r;
                smem[ml * 132 + nl] = (_Float16)(acc[mtl][ntl][r] + bv);
            }
    }
    __syncthreads();
    {
        int row = tid >> 2;        // 0..63
        int seg = tid & 3;         // 64B segment
        int m = m0 + row;
        if (m < NROW) {
            unsigned q = (unsigned)m / 50u;
            unsigned s = (unsigned)m - q * 50u;
            const char* src = (const char*)smem + row * 264 + seg * 64;
            char* dst = (char*)xproj2 + ((size_t)s * NSEQ + q) * 1024 + (size_t)n0 * 2 + seg * 64;
            for (int i = 0; i < 4; i++)
                *(u32x4*)(dst + i * 16) = *(const u32x4*)(src + i * 16);
        }
    }
}

// ---------------- LSTM: 100 blocks x 4 seqs x 8 waves (2 waves/SIMD) --------------------
// Wave w owns hid slice [w*16, w*16+16) for ALL 4 gates (4 gate-tiles, 16 MFMA/step).
// A rows replicated h[row&3] -> every quad holds all 4 seq-rows; quad q takes seq q
// (1 activation cell/lane, extracted with 8 cndmasks). 2 waves/SIMD overlap latency.
__global__ __launch_bounds__(512, 2) void lstm_kernel(const _Float16* __restrict__ xproj2,
                                                      const _Float16* __restrict__ whh,
                                                      _Float16* __restrict__ hseq) {
    int bid = blockIdx.x;        // 0..99
    int tid = threadIdx.x;
    int wave = tid >> 6;         // 0..7
    int lane = tid & 63;
    int quad = lane >> 4;        // = this lane's seq
    int col = lane & 15;
    int hid = wave * 16 + col;   // this lane's hid

    __shared__ __align__(16) char xbuf[2 * 4 * 1040];     // rows padded 1024->1040 B
    __shared__ __align__(16) _Float16 hbuf[2][4 * 136];   // [seq][hid], padded 128->136

    // B-frags: bfrag[g][kq]; B[k][n] = whh[g*128 + hid][k]
    f16x8 bfrag[4][4];
    for (int g = 0; g < 4; g++) {
        int n = g * 128 + hid;
        for (int kq = 0; kq < 4; kq++)
            bfrag[g][kq] = *(const f16x8*)(whh + (size_t)n * HID + kq * 32 + quad * 8);
    }
    for (int i = tid; i < 2 * 4 * 136; i += 512) ((_Float16*)hbuf)[i] = (_Float16)0.0f;
    float cst = 0.0f;
    _Float16 hprev = (_Float16)0.0f;

    const char* xsrc = (const char*)xproj2;
    // prefetch step 0 into xbuf[0]: 4 rows of 1KB; waves 0..3 stage one row each
    if (wave < 4)
        g2lds16(xsrc + (size_t)(bid * 4 + wave) * 1024 + lane * 16, xbuf + wave * 1040);
    __syncthreads();

    const f32x4 z4 = {0.f, 0.f, 0.f, 0.f};
    for (int s = 0; s < NSEG; s++) {
        int cur = s & 1;
        int nxt = cur ^ 1;

        // deferred global store of h_{s-1} (full step to drain before this step's barrier)
        if (s > 0)
            hseq[((size_t)(s - 1) * NSEQ + bid * 4 + quad) * HID + hid] = hprev;
        // prefetch step s+1
        if (s + 1 < NSEG && wave < 4)
            g2lds16(xsrc + ((size_t)(s + 1) * NSEQ + bid * 4 + wave) * 1024 + lane * 16,
                    xbuf + nxt * 4160 + wave * 1040);

        // A-frags: A[m][k] = h[m&3][k] (replicated rows)
        f16x8 afrag[4];
        for (int kq = 0; kq < 4; kq++)
            afrag[kq] = *(const f16x8*)(&hbuf[cur][(col & 3) * 136 + kq * 32 + quad * 8]);

        // x_proj gates from LDS: 4 scalar reads for this lane's (seq=quad, hid)
        float xp[4];
        for (int g = 0; g < 4; g++)
            xp[g] = (float)(*(const _Float16*)(xbuf + cur * 4160 +
                           quad * 1040 + (g * 128 + hid) * 2));

        f32x4 acc[4];
        for (int g = 0; g < 4; g++) {
            acc[g] = z4;
            for (int kq = 0; kq < 4; kq++)
                acc[g] = __builtin_amdgcn_mfma_f32_16x16x32_f16(afrag[kq], bfrag[g][kq], acc[g], 0, 0, 0);
        }

        // extract element [quad] of each gate vector (C row quad*4+r = seq r)
        float gv[4];
        for (int g = 0; g < 4; g++) {
            float lo = (quad & 1) ? acc[g][1] : acc[g][0];
            float hi = (quad & 1) ? acc[g][3] : acc[g][2];
            gv[g] = (quad & 2) ? hi : lo;
        }

        float ip = gv[0] + xp[0];
        float fp = gv[1] + xp[1];
        float gp = gv[2] + xp[2];
        float op = gv[3] + xp[3];
        float si = __fdividef(1.0f, 1.0f + __expf(-ip));
        float sf = __fdividef(1.0f, 1.0f + __expf(-fp));
        float so = __fdividef(1.0f, 1.0f + __expf(-op));
        float eg = __expf(-2.0f * gp);
        float tg = __fdividef(1.0f - eg, 1.0f + eg);
        cst = sf * cst + si * tg;
        float ec = __expf(-2.0f * cst);
        float tc = __fdividef(1.0f - ec, 1.0f + ec);
        float hv = so * tc;
        hprev = (_Float16)hv;
        hbuf[nxt][quad * 136 + hid] = hprev;
        __syncthreads();
    }
    // final store for s = 49
    hseq[((size_t)(NSEG - 1) * NSEQ + bid * 4 + quad) * HID + hid] = hprev;
}

// ---------------- transpose: out[b][hid][s][v] = hseq[s][b*25+v][hid] -------------------
__global__ __launch_bounds__(256) void tr_kernel(const _Float16* __restrict__ hseq,
                                                 float* __restrict__ out) {
    int bid = blockIdx.x;        // 0..799 = b*50+s
    int b = bid / NSEG;
    int s = bid - b * NSEG;
    int tid = threadIdx.x;

    __shared__ _Float16 buf[25 * 130];   // [v][hid], padded 128->130

    const uint32_t* src32 = (const uint32_t*)(hseq + ((size_t)s * NSEQ + b * 25) * HID);
    uint32_t* buf32 = (uint32_t*)buf;
    for (int i = tid; i < 1600; i += 256) {       // 25 rows x 64 dwords, contiguous read
        int v = i >> 6;
        int d = i & 63;
        buf32[v * 65 + d] = src32[i];
    }
    __syncthreads();
    for (int i = tid; i < 3200; i += 256) {
        int hid = i / 25;
        int v = i - hid * 25;
        out[(((size_t)b * 128 + hid) * NSEG + s) * 25 + v] = (float)buf[v * 130 + hid];
    }
}

extern "C" void kernel_launch(void* const* d_in, const int* in_sizes, int n_in,
                              void* d_out, int out_size, void* d_ws, size_t ws_size,
                              hipStream_t stream) {
    const float* x = (const float*)d_in[0];
    const float* Wih = (const float*)d_in[1];
    const float* Whh = (const float*)d_in[2];
    const float* bih = (const float*)d_in[3];
    const float* bhh = (const float*)d_in[4];
    float* out = (float*)d_out;

    char* ws = (char*)d_ws;
    size_t off = 0;
    _Float16* feat = (_Float16*)(ws + off);   off += (size_t)NROW_PAD * KD2 * 2;      // 87.5 MB
    _Float16* xproj2 = (_Float16*)(ws + off); off += (size_t)NSEG * NSEQ * GATES * 2; // 20.5 MB
    _Float16* hseq = (_Float16*)(ws + off);   off += (size_t)NSEG * NSEQ * HID * 2;   // 5.1 MB
    _Float16* wh = (_Float16*)(ws + off);     off += (size_t)512 * KD2 * 2;           // 2.2 MB
    _Float16* whh16 = (_Float16*)(ws + off);  off += (size_t)512 * HID * 2;
    float* bias = (float*)(ws + off);         off += 512 * 4;

    int prep_total = 512 * KD2 + 512 * HID + 512;
    hipLaunchKernelGGL(prep_kernel, dim3((prep_total + 255) / 256), dim3(256), 0, stream,
                       Wih, Whh, bih, bhh, wh, whh16, bias);
    hipLaunchKernelGGL(feat_kernel, dim3(16 * NSEG), dim3(256), 0, stream, x, feat);
    hipLaunchKernelGGL(gemm_kernel, dim3(314 * 4), dim3(256), 0, stream, feat, wh, bias, xproj2);
    hipLaunchKernelGGL(lstm_kernel, dim3(100), dim3(512), 0, stream, xproj2, whh16, hseq);
    hipLaunchKernelGGL(tr_kernel, dim3(16 * NSEG), dim3(256), 0, stream, hseq, out);
}

// Round 8
// 229.121 us; speedup vs baseline: 1.0566x; 1.0566x over previous
//
#include <hip/hip_runtime.h>
#include <stdint.h>

#define NSEG 50
#define HID 128
#define KDIM 2144      // 64 + 2016 + 64
#define KD2 2176       // padded to 34*64 for BK=64
#define KD2B 4352      // row bytes fp16
#define NROW 20000     // 400 * 50
#define NROW_PAD 20224 // 79 * 256
#define GATES 512
#define NSEQ 400

typedef __attribute__((ext_vector_type(8))) _Float16 f16x8;
typedef __attribute__((ext_vector_type(4))) float f32x4;
typedef __attribute__((ext_vector_type(4))) uint32_t u32x4;

#define GLB_SPACE __attribute__((address_space(1)))
#define LDS_SPACE __attribute__((address_space(3)))

__device__ __forceinline__ void g2lds16(const void* g, void* l) {
    __builtin_amdgcn_global_load_lds((const GLB_SPACE uint32_t*)g,
                                     (LDS_SPACE uint32_t*)l, 16, 0, 0);
}

// ---------------- prep: cast W_ih (K-padded) and W_hh to fp16, sum biases ---------------
__global__ __launch_bounds__(256) void prep_kernel(const float* __restrict__ Wih,
                                                   const float* __restrict__ Whh,
                                                   const float* __restrict__ bih,
                                                   const float* __restrict__ bhh,
                                                   _Float16* __restrict__ wh,
                                                   _Float16* __restrict__ whh16,
                                                   float* __restrict__ bias) {
    int idx = blockIdx.x * 256 + threadIdx.x;
    const int nwih = 512 * KD2;
    const int nwhh = 512 * HID;
    if (idx < nwih) {
        int row = idx / KD2;
        int k = idx - row * KD2;
        wh[idx] = (k < KDIM) ? (_Float16)Wih[row * KDIM + k] : (_Float16)0.0f;
    } else if (idx < nwih + nwhh) {
        int q = idx - nwih;
        whh16[q] = (_Float16)Whh[q];
    } else if (idx < nwih + nwhh + 512) {
        int g = idx - nwih - nwhh;
        bias[g] = bih[g] + bhh[g];
    }
}

// ---------------- features: one block per (b, s); rank-2 levy area ----------------------
// dev_0 == 0, so S2 = (p1-p0)x(p2-p1) + (p2-p0)x(p3-p2)
// uv4[c] = (u1,u2,v1,v2) packed -> 2 ds_read_b128 per pair instead of 4 ds_read_b64.
__global__ __launch_bounds__(256) void feat_kernel(const float* __restrict__ x,
                                                   _Float16* __restrict__ feat) {
    int bid = blockIdx.x;          // 0..799
    int b = bid / NSEG;
    int s = bid - b * NSEG;
    int tid = threadIdx.x;

    __shared__ float pbuf[64 * 100];          // p[c][t*25+v]
    __shared__ __align__(16) float4 uv4[25 * 64];   // (u1,u2,v1,v2) per (v,c)

    // load: x[b][c][4s+t][v] -> 100 contiguous floats per c
    for (int i = tid; i < 6400; i += 256) {
        int c = i / 100;
        int r = i - c * 100;
        pbuf[c * 100 + r] = x[(((size_t)b * 64 + c) * 200 + 4 * s) * 25 + r];
    }
    // zero the K-pad columns for this block's 25 rows
    if (tid < 800) {
        int v = tid >> 5;
        int k = 2144 + (tid & 31);
        size_t m = ((size_t)(b * 25 + v)) * NSEG + s;
        feat[m * KD2 + k] = (_Float16)0.0f;
    }
    __syncthreads();

    // derived vectors + lvl1/start features
    for (int i = tid; i < 1600; i += 256) {
        int v = i >> 6;
        int c = i & 63;
        float p0 = pbuf[c * 100 + v];
        float p1 = pbuf[c * 100 + 25 + v];
        float p2 = pbuf[c * 100 + 50 + v];
        float p3 = pbuf[c * 100 + 75 + v];
        uv4[v * 64 + c] = make_float4(p1 - p0, p2 - p0, p2 - p1, p3 - p2);
        size_t m = ((size_t)(b * 25 + v)) * NSEG + s;
        feat[m * KD2 + c] = (_Float16)(p3 - p0);             // lvl1
        feat[m * KD2 + 2080 + c] = (_Float16)p0;             // start
    }
    __syncthreads();

    // levy: 2016 upper-triangle pairs, threads over k (coalesced 2B stores), v inner
    for (int ch = 0; ch < 8; ch++) {
        int pidx = ch * 256 + tid;
        if (pidx < 2016) {
            float disc = 16129.0f - 8.0f * (float)pidx;      // (127-2i)^2 at row starts
            int i = (int)((127.0f - sqrtf(disc)) * 0.5f);
            int off = 63 * i - (i * (i - 1)) / 2;
            while (off > pidx) { i--; off = 63 * i - (i * (i - 1)) / 2; }
            while (63 * (i + 1) - ((i + 1) * i) / 2 <= pidx) { i++; off = 63 * i - (i * (i - 1)) / 2; }
            int j = pidx - off + i + 1;
            int k = 64 + pidx;
            for (int v = 0; v < 25; v++) {
                float4 a = uv4[v * 64 + i];
                float4 bb = uv4[v * 64 + j];
                float val = 0.5f * (a.x * bb.z - bb.x * a.z + a.y * bb.w - bb.y * a.w);
                size_t m = ((size_t)(b * 25 + v)) * NSEG + s;
                feat[m * KD2 + k] = (_Float16)val;
            }
        }
    }
}

// ---------------- GEMM: xproj2[s][q][gate] = feat @ W_ih^T + bias (fp16 out) ------------
// BM=256, BN=128, BK=64; grid 316 = 79*4 (all ~co-resident at 2 blocks/CU).
// Staging = 525 MB (vs 668 at 128x128): 192 B staged per MFMA instr.
// 8 waves, wave tile 64x64. XOR-swizzled LDS rows (keyed on row%8), zero conflicts (r6).
__global__ __launch_bounds__(512, 4) void gemm_kernel(const _Float16* __restrict__ feat,
                                                      const _Float16* __restrict__ wh,
                                                      const float* __restrict__ bias,
                                                      _Float16* __restrict__ xproj2) {
    int bid = blockIdx.x;
    int nb = bid & 3;
    int mt = bid >> 2;             // 0..78
    int m0 = mt * 256;
    int n0 = nb * 128;
    int tid = threadIdx.x;
    int wave = tid >> 6;           // 0..7
    int lane = tid & 63;
    int quad = lane >> 4;
    int l15 = lane & 15;
    int wm = (wave & 3) * 64;      // 0/64/128/192
    int wn = (wave >> 2) * 64;     // 0/64

    int r8 = lane >> 3;                        // row within 8-row staging group
    int gcol = ((lane & 7) * 16) ^ (r8 * 16);  // XOR-swizzled source byte-col

    __shared__ __align__(16) _Float16 smem[256 * 132];   // 67.6 KB (K-loop uses 48 KB)
    char* As = (char*)smem;                    // 256 rows x 128 B = 32 KB
    char* Bs = (char*)smem + 32768;            // 128 rows x 128 B = 16 KB

    const f32x4 z4 = {0.f, 0.f, 0.f, 0.f};
    f32x4 acc[4][4];
    for (int i = 0; i < 4; i++)
        for (int j = 0; j < 4; j++) acc[i][j] = z4;

    const char* featB = (const char*)feat;
    const char* whB = (const char*)wh;

    for (int kt = 0; kt < 34; kt++) {
        size_t kb = (size_t)kt * 128;
        __syncthreads();
        for (int it = 0; it < 4; it++) {       // A: 256 rows
            int rb = it * 64 + wave * 8;
            g2lds16(featB + (size_t)(m0 + rb + r8) * KD2B + kb + gcol, As + rb * 128);
        }
        for (int it = 0; it < 2; it++) {       // B: 128 rows
            int rb = it * 64 + wave * 8;
            g2lds16(whB + (size_t)(n0 + rb + r8) * KD2B + kb + gcol, Bs + rb * 128);
        }
        __syncthreads();

        for (int ks = 0; ks < 2; ks++) {
            int off = ((ks * 64) | (quad * 16)) ^ ((l15 & 7) * 16);
            f16x8 af[4], bf[4];
            for (int tt = 0; tt < 4; tt++) {
                af[tt] = *(const f16x8*)(As + (wm + tt * 16 + l15) * 128 + off);
                bf[tt] = *(const f16x8*)(Bs + (wn + tt * 16 + l15) * 128 + off);
            }
            for (int mtl = 0; mtl < 4; mtl++)
                for (int ntl = 0; ntl < 4; ntl++)
                    acc[mtl][ntl] = __builtin_amdgcn_mfma_f32_16x16x32_f16(af[mtl], bf[ntl], acc[mtl][ntl], 0, 0, 0);
        }
    }

    // epilogue: stage fp16 tile (256x128) in LDS, row stride 132 halfwords
    __syncthreads();
    for (int ntl = 0; ntl < 4; ntl++) {
        int nl = wn + ntl * 16 + l15;
        float bv = bias[n0 + nl];
        for (int mtl = 0; mtl < 4; mtl++)
            for (int r = 0; r < 4; r++) {
                int ml = wm + mtl * 16 + quad * 4 + r;
                smem[ml * 132 + nl] = (_Float16)(acc[mtl][ntl][r] + bv);
            }
    }
    __syncthreads();
    {
        int row = tid >> 1;        // 0..255
        int seg = tid & 1;         // 128B segment
        int m = m0 + row;
        if (m < NROW) {
            unsigned q = (unsigned)m / 50u;
            unsigned s = (unsigned)m - q * 50u;
            const char* src = (const char*)smem + row * 264 + seg * 128;
            char* dst = (char*)xproj2 + ((size_t)s * NSEQ + q) * 1024 + (size_t)n0 * 2 + seg * 128;
            for (int i = 0; i < 8; i++)
                *(u32x4*)(dst + i * 16) = *(const u32x4*)(src + i * 16);
        }
    }
}

// ---------------- LSTM: 100 blocks x 4 seqs x 8 waves (2 waves/SIMD) --------------------
// Wave w owns hid slice [w*16, w*16+16) for ALL 4 gates (4 gate-tiles, 16 MFMA/step).
// A rows replicated h[row&3] -> every quad holds all 4 seq-rows; quad q takes seq q
// (1 activation cell/lane). hseq stores deferred one step (drain before the barrier).
__global__ __launch_bounds__(512, 2) void lstm_kernel(const _Float16* __restrict__ xproj2,
                                                      const _Float16* __restrict__ whh,
                                                      _Float16* __restrict__ hseq) {
    int bid = blockIdx.x;        // 0..99
    int tid = threadIdx.x;
    int wave = tid >> 6;         // 0..7
    int lane = tid & 63;
    int quad = lane >> 4;        // = this lane's seq
    int col = lane & 15;
    int hid = wave * 16 + col;   // this lane's hid

    __shared__ __align__(16) char xbuf[2 * 4 * 1040];     // rows padded 1024->1040 B
    __shared__ __align__(16) _Float16 hbuf[2][4 * 136];   // [seq][hid], padded 128->136

    // B-frags: bfrag[g][kq]; B[k][n] = whh[g*128 + hid][k]
    f16x8 bfrag[4][4];
    for (int g = 0; g < 4; g++) {
        int n = g * 128 + hid;
        for (int kq = 0; kq < 4; kq++)
            bfrag[g][kq] = *(const f16x8*)(whh + (size_t)n * HID + kq * 32 + quad * 8);
    }
    for (int i = tid; i < 2 * 4 * 136; i += 512) ((_Float16*)hbuf)[i] = (_Float16)0.0f;
    float cst = 0.0f;
    _Float16 hprev = (_Float16)0.0f;

    const char* xsrc = (const char*)xproj2;
    // prefetch step 0 into xbuf[0]: 4 rows of 1KB; waves 0..3 stage one row each
    if (wave < 4)
        g2lds16(xsrc + (size_t)(bid * 4 + wave) * 1024 + lane * 16, xbuf + wave * 1040);
    __syncthreads();

    const f32x4 z4 = {0.f, 0.f, 0.f, 0.f};
    for (int s = 0; s < NSEG; s++) {
        int cur = s & 1;
        int nxt = cur ^ 1;

        // deferred global store of h_{s-1} (full step to drain before this step's barrier)
        if (s > 0)
            hseq[((size_t)(s - 1) * NSEQ + bid * 4 + quad) * HID + hid] = hprev;
        // prefetch step s+1
        if (s + 1 < NSEG && wave < 4)
            g2lds16(xsrc + ((size_t)(s + 1) * NSEQ + bid * 4 + wave) * 1024 + lane * 16,
                    xbuf + nxt * 4160 + wave * 1040);

        // A-frags: A[m][k] = h[m&3][k] (replicated rows)
        f16x8 afrag[4];
        for (int kq = 0; kq < 4; kq++)
            afrag[kq] = *(const f16x8*)(&hbuf[cur][(col & 3) * 136 + kq * 32 + quad * 8]);

        // x_proj gates from LDS: 4 scalar reads for this lane's (seq=quad, hid)
        float xp[4];
        for (int g = 0; g < 4; g++)
            xp[g] = (float)(*(const _Float16*)(xbuf + cur * 4160 +
                           quad * 1040 + (g * 128 + hid) * 2));

        f32x4 acc[4];
        for (int g = 0; g < 4; g++) {
            acc[g] = z4;
            for (int kq = 0; kq < 4; kq++)
                acc[g] = __builtin_amdgcn_mfma_f32_16x16x32_f16(afrag[kq], bfrag[g][kq], acc[g], 0, 0, 0);
        }

        // extract element [quad] of each gate vector (C row quad*4+r = seq r)
        float gv[4];
        for (int g = 0; g < 4; g++) {
            float lo = (quad & 1) ? acc[g][1] : acc[g][0];
            float hi = (quad & 1) ? acc[g][3] : acc[g][2];
            gv[g] = (quad & 2) ? hi : lo;
        }

        float ip = gv[0] + xp[0];
        float fp = gv[1] + xp[1];
        float gp = gv[2] + xp[2];
        float op = gv[3] + xp[3];
        float si = __fdividef(1.0f, 1.0f + __expf(-ip));
        float sf = __fdividef(1.0f, 1.0f + __expf(-fp));
        float so = __fdividef(1.0f, 1.0f + __expf(-op));
        float eg = __expf(-2.0f * gp);
        float tg = __fdividef(1.0f - eg, 1.0f + eg);
        cst = sf * cst + si * tg;
        float ec = __expf(-2.0f * cst);
        float tc = __fdividef(1.0f - ec, 1.0f + ec);
        float hv = so * tc;
        hprev = (_Float16)hv;
        hbuf[nxt][quad * 136 + hid] = hprev;
        __syncthreads();
    }
    // final store for s = 49
    hseq[((size_t)(NSEG - 1) * NSEQ + bid * 4 + quad) * HID + hid] = hprev;
}

// ---------------- transpose: out[b][hid][s][v] = hseq[s][b*25+v][hid] -------------------
__global__ __launch_bounds__(256) void tr_kernel(const _Float16* __restrict__ hseq,
                                                 float* __restrict__ out) {
    int bid = blockIdx.x;        // 0..799 = b*50+s
    int b = bid / NSEG;
    int s = bid - b * NSEG;
    int tid = threadIdx.x;

    __shared__ _Float16 buf[25 * 130];   // [v][hid], padded 128->130

    const uint32_t* src32 = (const uint32_t*)(hseq + ((size_t)s * NSEQ + b * 25) * HID);
    uint32_t* buf32 = (uint32_t*)buf;
    for (int i = tid; i < 1600; i += 256) {       // 25 rows x 64 dwords, contiguous read
        int v = i >> 6;
        int d = i & 63;
        buf32[v * 65 + d] = src32[i];
    }
    __syncthreads();
    for (int i = tid; i < 3200; i += 256) {
        int hid = i / 25;
        int v = i - hid * 25;
        out[(((size_t)b * 128 + hid) * NSEG + s) * 25 + v] = (float)buf[v * 130 + hid];
    }
}

extern "C" void kernel_launch(void* const* d_in, const int* in_sizes, int n_in,
                              void* d_out, int out_size, void* d_ws, size_t ws_size,
                              hipStream_t stream) {
    const float* x = (const float*)d_in[0];
    const float* Wih = (const float*)d_in[1];
    const float* Whh = (const float*)d_in[2];
    const float* bih = (const float*)d_in[3];
    const float* bhh = (const float*)d_in[4];
    float* out = (float*)d_out;

    char* ws = (char*)d_ws;
    size_t off = 0;
    _Float16* feat = (_Float16*)(ws + off);   off += (size_t)NROW_PAD * KD2 * 2;      // 88.0 MB
    _Float16* xproj2 = (_Float16*)(ws + off); off += (size_t)NSEG * NSEQ * GATES * 2; // 20.5 MB
    _Float16* hseq = (_Float16*)(ws + off);   off += (size_t)NSEG * NSEQ * HID * 2;   // 5.1 MB
    _Float16* wh = (_Float16*)(ws + off);     off += (size_t)512 * KD2 * 2;           // 2.2 MB
    _Float16* whh16 = (_Float16*)(ws + off);  off += (size_t)512 * HID * 2;
    float* bias = (float*)(ws + off);         off += 512 * 4;

    int prep_total = 512 * KD2 + 512 * HID + 512;
    hipLaunchKernelGGL(prep_kernel, dim3((prep_total + 255) / 256), dim3(256), 0, stream,
                       Wih, Whh, bih, bhh, wh, whh16, bias);
    hipLaunchKernelGGL(feat_kernel, dim3(16 * NSEG), dim3(256), 0, stream, x, feat);
    hipLaunchKernelGGL(gemm_kernel, dim3(79 * 4), dim3(512), 0, stream, feat, wh, bias, xproj2);
    hipLaunchKernelGGL(lstm_kernel, dim3(100), dim3(512), 0, stream, xproj2, whh16, hseq);
    hipLaunchKernelGGL(tr_kernel, dim3(16 * NSEG), dim3(256), 0, stream, hseq, out);
}

// Round 9
// 220.474 us; speedup vs baseline: 1.0981x; 1.0392x over previous
//
#include <hip/hip_runtime.h>
#include <stdint.h>

#define NSEG 50
#define HID 128
#define KDIM 2144      // 64 + 2016 + 64
#define KD2 2176       // padded to 34*64 for BK=64
#define KD2B 4352      // row bytes fp16
#define NROW 20000     // 400 * 50
#define NROW_PAD 20096 // 157 * 128
#define GATES 512
#define NSEQ 400

typedef __attribute__((ext_vector_type(8))) _Float16 f16x8;
typedef __attribute__((ext_vector_type(4))) float f32x4;
typedef __attribute__((ext_vector_type(4))) uint32_t u32x4;

#define GLB_SPACE __attribute__((address_space(1)))
#define LDS_SPACE __attribute__((address_space(3)))

__device__ __forceinline__ void g2lds16(const void* g, void* l) {
    __builtin_amdgcn_global_load_lds((const GLB_SPACE uint32_t*)g,
                                     (LDS_SPACE uint32_t*)l, 16, 0, 0);
}

// ---------------- prep: cast W_ih (K-padded) and W_hh to fp16, sum biases ---------------
__global__ __launch_bounds__(256) void prep_kernel(const float* __restrict__ Wih,
                                                   const float* __restrict__ Whh,
                                                   const float* __restrict__ bih,
                                                   const float* __restrict__ bhh,
                                                   _Float16* __restrict__ wh,
                                                   _Float16* __restrict__ whh16,
                                                   float* __restrict__ bias) {
    int idx = blockIdx.x * 256 + threadIdx.x;
    const int nwih = 512 * KD2;
    const int nwhh = 512 * HID;
    if (idx < nwih) {
        int row = idx / KD2;
        int k = idx - row * KD2;
        wh[idx] = (k < KDIM) ? (_Float16)Wih[row * KDIM + k] : (_Float16)0.0f;
    } else if (idx < nwih + nwhh) {
        int q = idx - nwih;
        whh16[q] = (_Float16)Whh[q];
    } else if (idx < nwih + nwhh + 512) {
        int g = idx - nwih - nwhh;
        bias[g] = bih[g] + bhh[g];
    }
}

// ---------------- features: one block per (b, s); rank-2 levy area ----------------------
// dev_0 == 0, so S2 = (p1-p0)x(p2-p1) + (p2-p0)x(p3-p2)
// uv4[c] = (u1,u2,v1,v2) packed -> 2 ds_read_b128 per pair instead of 4 ds_read_b64.
__global__ __launch_bounds__(256) void feat_kernel(const float* __restrict__ x,
                                                   _Float16* __restrict__ feat) {
    int bid = blockIdx.x;          // 0..799
    int b = bid / NSEG;
    int s = bid - b * NSEG;
    int tid = threadIdx.x;

    __shared__ float pbuf[64 * 100];          // p[c][t*25+v]
    __shared__ __align__(16) float4 uv4[25 * 64];   // (u1,u2,v1,v2) per (v,c)

    // load: x[b][c][4s+t][v] -> 100 contiguous floats per c
    for (int i = tid; i < 6400; i += 256) {
        int c = i / 100;
        int r = i - c * 100;
        pbuf[c * 100 + r] = x[(((size_t)b * 64 + c) * 200 + 4 * s) * 25 + r];
    }
    // zero the K-pad columns for this block's 25 rows
    if (tid < 800) {
        int v = tid >> 5;
        int k = 2144 + (tid & 31);
        size_t m = ((size_t)(b * 25 + v)) * NSEG + s;
        feat[m * KD2 + k] = (_Float16)0.0f;
    }
    __syncthreads();

    // derived vectors + lvl1/start features
    for (int i = tid; i < 1600; i += 256) {
        int v = i >> 6;
        int c = i & 63;
        float p0 = pbuf[c * 100 + v];
        float p1 = pbuf[c * 100 + 25 + v];
        float p2 = pbuf[c * 100 + 50 + v];
        float p3 = pbuf[c * 100 + 75 + v];
        uv4[v * 64 + c] = make_float4(p1 - p0, p2 - p0, p2 - p1, p3 - p2);
        size_t m = ((size_t)(b * 25 + v)) * NSEG + s;
        feat[m * KD2 + c] = (_Float16)(p3 - p0);             // lvl1
        feat[m * KD2 + 2080 + c] = (_Float16)p0;             // start
    }
    __syncthreads();

    // levy: 2016 upper-triangle pairs, threads over k (coalesced 2B stores), v inner
    for (int ch = 0; ch < 8; ch++) {
        int pidx = ch * 256 + tid;
        if (pidx < 2016) {
            float disc = 16129.0f - 8.0f * (float)pidx;      // (127-2i)^2 at row starts
            int i = (int)((127.0f - sqrtf(disc)) * 0.5f);
            int off = 63 * i - (i * (i - 1)) / 2;
            while (off > pidx) { i--; off = 63 * i - (i * (i - 1)) / 2; }
            while (63 * (i + 1) - ((i + 1) * i) / 2 <= pidx) { i++; off = 63 * i - (i * (i - 1)) / 2; }
            int j = pidx - off + i + 1;
            int k = 64 + pidx;
            for (int v = 0; v < 25; v++) {
                float4 a = uv4[v * 64 + i];
                float4 bb = uv4[v * 64 + j];
                float val = 0.5f * (a.x * bb.z - bb.x * a.z + a.y * bb.w - bb.y * a.w);
                size_t m = ((size_t)(b * 25 + v)) * NSEG + s;
                feat[m * KD2 + k] = (_Float16)val;
            }
        }
    }
}

// ---------------- GEMM (r6 config): xproj2[s][q][gate] = feat @ W_ih^T + bias -----------
// BM=128, BN=128, BK=64; grid 640. bid&7-major mapping keeps the 4 n-siblings of each
// m-tile within a 32-bid window on one XCD residue class: A-tile L2/LLC-deduped
// (measured r6: FETCH 52 MB, 65 us). Epilogue staged via LDS, 256B-row dwordx4 stores.
__global__ __launch_bounds__(256, 3) void gemm_kernel(const _Float16* __restrict__ feat,
                                                      const _Float16* __restrict__ wh,
                                                      const float* __restrict__ bias,
                                                      _Float16* __restrict__ xproj2) {
    int bid = blockIdx.x;
    int x = bid & 7;
    int t = bid >> 3;
    int nb = t & 3;
    int mt = (t >> 2) * 8 + x;
    if (mt >= 157) return;
    int m0 = mt * 128;
    int n0 = nb * 128;
    int tid = threadIdx.x;
    int wave = tid >> 6;
    int lane = tid & 63;
    int quad = lane >> 4;
    int l15 = lane & 15;
    int wm = (wave & 1) * 64;
    int wn = (wave >> 1) * 64;

    int r8 = lane >> 3;                        // row within 8-row staging group
    int gcol = ((lane & 7) * 16) ^ (r8 * 16);  // XOR-swizzled source byte-col

    __shared__ __align__(16) _Float16 smem[16896];   // 33 KB (K-loop 32 KB; epilogue 128x132)
    char* As = (char*)smem;                    // 128 rows x 128 B
    char* Bs = (char*)smem + 128 * 128;        // 128 rows x 128 B

    const f32x4 z4 = {0.f, 0.f, 0.f, 0.f};
    f32x4 acc[4][4];
    for (int i = 0; i < 4; i++)
        for (int j = 0; j < 4; j++) acc[i][j] = z4;

    const char* featB = (const char*)feat;
    const char* whB = (const char*)wh;

    for (int kt = 0; kt < 34; kt++) {
        size_t kb = (size_t)kt * 128;
        __syncthreads();
        for (int it = 0; it < 4; it++) {
            int rb = it * 32 + wave * 8;
            g2lds16(featB + (size_t)(m0 + rb + r8) * KD2B + kb + gcol, As + rb * 128);
            g2lds16(whB + (size_t)(n0 + rb + r8) * KD2B + kb + gcol, Bs + rb * 128);
        }
        __syncthreads();

        for (int ks = 0; ks < 2; ks++) {
            int off = ((ks * 64) | (quad * 16)) ^ ((l15 & 7) * 16);
            f16x8 af[4], bf[4];
            for (int tt = 0; tt < 4; tt++) {
                af[tt] = *(const f16x8*)(As + (wm + tt * 16 + l15) * 128 + off);
                bf[tt] = *(const f16x8*)(Bs + (wn + tt * 16 + l15) * 128 + off);
            }
            for (int mtl = 0; mtl < 4; mtl++)
                for (int ntl = 0; ntl < 4; ntl++)
                    acc[mtl][ntl] = __builtin_amdgcn_mfma_f32_16x16x32_f16(af[mtl], bf[ntl], acc[mtl][ntl], 0, 0, 0);
        }
    }

    // epilogue: stage fp16 tile in LDS (row stride 132 halfwords -> conflict-free writes)
    __syncthreads();
    for (int ntl = 0; ntl < 4; ntl++) {
        int nl = wn + ntl * 16 + l15;
        float bv = bias[n0 + nl];
        for (int mtl = 0; mtl < 4; mtl++)
            for (int r = 0; r < 4; r++) {
                int ml = wm + mtl * 16 + quad * 4 + r;
                smem[ml * 132 + nl] = (_Float16)(acc[mtl][ntl][r] + bv);
            }
    }
    __syncthreads();
    {
        int row = tid >> 1;
        int seg = tid & 1;
        int m = m0 + row;
        if (m < NROW) {
            unsigned q = (unsigned)m / 50u;
            unsigned s = (unsigned)m - q * 50u;
            const char* src = (const char*)smem + row * 264 + seg * 128;
            char* dst = (char*)xproj2 + ((size_t)s * NSEQ + q) * 1024 + (size_t)n0 * 2 + seg * 128;
            for (int i = 0; i < 8; i++)
                *(u32x4*)(dst + i * 16) = *(const u32x4*)(src + i * 16);
        }
    }
}

// ---------------- LSTM: 100 blocks x 4 seqs x 8 waves; NO per-step global ops -----------
// 25 steps of xproj preloaded into LDS (104 KB), refilled once at midpoint; all h
// outputs buffered in LDS (51 KB) and written out coalesced at the end. Steady-state
// step = LDS + MFMA + VALU + barrier only (no vmcnt drain on the critical path).
// Wave w owns hid [w*16,w*16+16) for all 4 gates; A rows replicated h[row&3]; quad=seq.
__global__ __launch_bounds__(512, 2) void lstm_kernel(const _Float16* __restrict__ xproj2,
                                                      const _Float16* __restrict__ whh,
                                                      _Float16* __restrict__ hseq) {
    int bid = blockIdx.x;        // 0..99
    int tid = threadIdx.x;
    int wave = tid >> 6;         // 0..7
    int lane = tid & 63;
    int quad = lane >> 4;        // = this lane's seq
    int col = lane & 15;
    int hid = wave * 16 + col;   // this lane's hid

    __shared__ __align__(16) char xbuf[25 * 4 * 1040];       // 104,000 B, rows padded
    __shared__ __align__(16) _Float16 hst[NSEG * 4 * HID];   // 51,200 B, [s][seq][hid]
    __shared__ __align__(16) _Float16 hbuf[2][4 * 144];      // 2,304 B, stride 144

    // B-frags: bfrag[g][kq]; B[k][n] = whh[g*128 + hid][k]
    f16x8 bfrag[4][4];
    for (int g = 0; g < 4; g++) {
        int n = g * 128 + hid;
        for (int kq = 0; kq < 4; kq++)
            bfrag[g][kq] = *(const f16x8*)(whh + (size_t)n * HID + kq * 32 + quad * 8);
    }
    for (int i = tid; i < 2 * 4 * 144; i += 512) ((_Float16*)hbuf)[i] = (_Float16)0.0f;
    float cst = 0.0f;

    const char* xsrc = (const char*)xproj2;
    // preload steps 0..24 (100 rows of 1 KB), 12-13 g2lds per wave
    for (int r = wave; r < 100; r += 8)
        g2lds16(xsrc + ((size_t)((r >> 2) * NSEQ + bid * 4 + (r & 3))) * 1024 + lane * 16,
                xbuf + r * 1040);
    __syncthreads();

    const f32x4 z4 = {0.f, 0.f, 0.f, 0.f};
    for (int half = 0; half < 2; half++) {
        for (int ss = 0; ss < 25; ss++) {
            int s = half * 25 + ss;
            int cur = s & 1;
            int nxt = cur ^ 1;

            // A-frags: A[m][k] = h[m&3][k] (replicated rows)
            f16x8 afrag[4];
            for (int kq = 0; kq < 4; kq++)
                afrag[kq] = *(const f16x8*)(&hbuf[cur][(col & 3) * 144 + kq * 32 + quad * 8]);

            // x_proj gates from LDS: 4 scalar reads for (seq=quad, hid)
            float xp[4];
            for (int g = 0; g < 4; g++)
                xp[g] = (float)(*(const _Float16*)(xbuf + (ss * 4 + quad) * 1040 +
                               (g * 128 + hid) * 2));

            f32x4 acc[4];
            for (int g = 0; g < 4; g++) {
                acc[g] = z4;
                for (int kq = 0; kq < 4; kq++)
                    acc[g] = __builtin_amdgcn_mfma_f32_16x16x32_f16(afrag[kq], bfrag[g][kq], acc[g], 0, 0, 0);
            }

            // extract element [quad] of each gate vector (C row quad*4+r = seq r)
            float gv[4];
            for (int g = 0; g < 4; g++) {
                float lo = (quad & 1) ? acc[g][1] : acc[g][0];
                float hi = (quad & 1) ? acc[g][3] : acc[g][2];
                gv[g] = (quad & 2) ? hi : lo;
            }

            float ip = gv[0] + xp[0];
            float fp = gv[1] + xp[1];
            float gp = gv[2] + xp[2];
            float op = gv[3] + xp[3];
            float si = __fdividef(1.0f, 1.0f + __expf(-ip));
            float sf = __fdividef(1.0f, 1.0f + __expf(-fp));
            float so = __fdividef(1.0f, 1.0f + __expf(-op));
            float eg = __expf(-2.0f * gp);
            float tg = __fdividef(1.0f - eg, 1.0f + eg);
            cst = sf * cst + si * tg;
            float ec = __expf(-2.0f * cst);
            float tc = __fdividef(1.0f - ec, 1.0f + ec);
            float hv = so * tc;
            _Float16 hv16 = (_Float16)hv;
            hbuf[nxt][quad * 144 + hid] = hv16;
            hst[(s * 4 + quad) * 128 + hid] = hv16;
            __syncthreads();
        }
        if (half == 0) {
            // refill slots 0..24 with steps 25..49 (one-time vmcnt drain)
            for (int r = wave; r < 100; r += 8)
                g2lds16(xsrc + ((size_t)((25 + (r >> 2)) * NSEQ + bid * 4 + (r & 3))) * 1024 + lane * 16,
                        xbuf + r * 1040);
            __syncthreads();
        }
    }

    // coalesced writeout of all 50 steps: 3200 dwordx4
    const u32x4* src = (const u32x4*)hst;
    for (int i = tid; i < 3200; i += 512) {
        int s = i >> 6;            // 64 vec4 per step
        int rem = i & 63;
        int seq = rem >> 4;
        int seg = rem & 15;
        u32x4 v = src[i];
        *(u32x4*)((char*)hseq + ((size_t)(s * NSEQ + bid * 4 + seq)) * 256 + seg * 16) = v;
    }
}

// ---------------- transpose: out[b][hid][s][v] = hseq[s][b*25+v][hid] -------------------
__global__ __launch_bounds__(256) void tr_kernel(const _Float16* __restrict__ hseq,
                                                 float* __restrict__ out) {
    int bid = blockIdx.x;        // 0..799 = b*50+s
    int b = bid / NSEG;
    int s = bid - b * NSEG;
    int tid = threadIdx.x;

    __shared__ _Float16 buf[25 * 130];   // [v][hid], padded 128->130

    const uint32_t* src32 = (const uint32_t*)(hseq + ((size_t)s * NSEQ + b * 25) * HID);
    uint32_t* buf32 = (uint32_t*)buf;
    for (int i = tid; i < 1600; i += 256) {       // 25 rows x 64 dwords, contiguous read
        int v = i >> 6;
        int d = i & 63;
        buf32[v * 65 + d] = src32[i];
    }
    __syncthreads();
    for (int i = tid; i < 3200; i += 256) {
        int hid = i / 25;
        int v = i - hid * 25;
        out[(((size_t)b * 128 + hid) * NSEG + s) * 25 + v] = (float)buf[v * 130 + hid];
    }
}

extern "C" void kernel_launch(void* const* d_in, const int* in_sizes, int n_in,
                              void* d_out, int out_size, void* d_ws, size_t ws_size,
                              hipStream_t stream) {
    const float* x = (const float*)d_in[0];
    const float* Wih = (const float*)d_in[1];
    const float* Whh = (const float*)d_in[2];
    const float* bih = (const float*)d_in[3];
    const float* bhh = (const float*)d_in[4];
    float* out = (float*)d_out;

    char* ws = (char*)d_ws;
    size_t off = 0;
    _Float16* feat = (_Float16*)(ws + off);   off += (size_t)NROW_PAD * KD2 * 2;      // 87.5 MB
    _Float16* xproj2 = (_Float16*)(ws + off); off += (size_t)NSEG * NSEQ * GATES * 2; // 20.5 MB
    _Float16* hseq = (_Float16*)(ws + off);   off += (size_t)NSEG * NSEQ * HID * 2;   // 5.1 MB
    _Float16* wh = (_Float16*)(ws + off);     off += (size_t)512 * KD2 * 2;           // 2.2 MB
    _Float16* whh16 = (_Float16*)(ws + off);  off += (size_t)512 * HID * 2;
    float* bias = (float*)(ws + off);         off += 512 * 4;

    int prep_total = 512 * KD2 + 512 * HID + 512;
    hipLaunchKernelGGL(prep_kernel, dim3((prep_total + 255) / 256), dim3(256), 0, stream,
                       Wih, Whh, bih, bhh, wh, whh16, bias);
    hipLaunchKernelGGL(feat_kernel, dim3(16 * NSEG), dim3(256), 0, stream, x, feat);
    hipLaunchKernelGGL(gemm_kernel, dim3(640), dim3(256), 0, stream, feat, wh, bias, xproj2);
    hipLaunchKernelGGL(lstm_kernel, dim3(100), dim3(512), 0, stream, xproj2, whh16, hseq);
    hipLaunchKernelGGL(tr_kernel, dim3(16 * NSEG), dim3(256), 0, stream, hseq, out);
}

// Round 10
// 220.228 us; speedup vs baseline: 1.0993x; 1.0011x over previous
//
#include <hip/hip_runtime.h>
#include <stdint.h>

#define NSEG 50
#define HID 128
#define KDIM 2144      // 64 + 2016 + 64
#define KD2 2176       // padded to 34*64 for BK=64
#define KD2B 4352      // row bytes fp16
#define NROW 20000     // 400 * 50
#define NROW_PAD 20096 // 157 * 128
#define GATES 512
#define NSEQ 400

typedef __attribute__((ext_vector_type(8))) _Float16 f16x8;
typedef __attribute__((ext_vector_type(4))) float f32x4;
typedef __attribute__((ext_vector_type(4))) uint32_t u32x4;

#define GLB_SPACE __attribute__((address_space(1)))
#define LDS_SPACE __attribute__((address_space(3)))

__device__ __forceinline__ void g2lds16(const void* g, void* l) {
    __builtin_amdgcn_global_load_lds((const GLB_SPACE uint32_t*)g,
                                     (LDS_SPACE uint32_t*)l, 16, 0, 0);
}

// ---------------- features (blocks 0..799) + fused weight-prep (blocks 800..863) --------
// dev_0 == 0, so S2 = (p1-p0)x(p2-p1) + (p2-p0)x(p3-p2)
__global__ __launch_bounds__(256) void feat_kernel(const float* __restrict__ x,
                                                   const float* __restrict__ Wih,
                                                   const float* __restrict__ Whh,
                                                   const float* __restrict__ bih,
                                                   const float* __restrict__ bhh,
                                                   _Float16* __restrict__ feat,
                                                   _Float16* __restrict__ wh,
                                                   _Float16* __restrict__ whh16,
                                                   float* __restrict__ bias) {
    int bid = blockIdx.x;
    int tid = threadIdx.x;

    if (bid >= 800) {
        // ---- prep path: cast W_ih (K-padded) and W_hh to fp16, sum biases ----
        const int nwih = 512 * KD2;
        const int nwhh = 512 * HID;
        const int total = nwih + nwhh + 512;
        for (int idx = (bid - 800) * 256 + tid; idx < total; idx += 64 * 256) {
            if (idx < nwih) {
                int row = idx / KD2;
                int k = idx - row * KD2;
                wh[idx] = (k < KDIM) ? (_Float16)Wih[row * KDIM + k] : (_Float16)0.0f;
            } else if (idx < nwih + nwhh) {
                int q = idx - nwih;
                whh16[q] = (_Float16)Whh[q];
            } else {
                int g = idx - nwih - nwhh;
                bias[g] = bih[g] + bhh[g];
            }
        }
        return;
    }

    int b = bid / NSEG;
    int s = bid - b * NSEG;

    __shared__ float pbuf[64 * 100];                // p[c][t*25+v]
    __shared__ __align__(16) float4 uv4[25 * 64];   // (u1,u2,v1,v2) per (v,c)

    // load: x[b][c][4s+t][v] -> 100 contiguous floats per c
    for (int i = tid; i < 6400; i += 256) {
        int c = i / 100;
        int r = i - c * 100;
        pbuf[c * 100 + r] = x[(((size_t)b * 64 + c) * 200 + 4 * s) * 25 + r];
    }
    // zero the K-pad columns for this block's 25 rows
    if (tid < 800) {
        int v = tid >> 5;
        int k = 2144 + (tid & 31);
        size_t m = ((size_t)(b * 25 + v)) * NSEG + s;
        feat[m * KD2 + k] = (_Float16)0.0f;
    }
    __syncthreads();

    // derived vectors + lvl1/start features
    for (int i = tid; i < 1600; i += 256) {
        int v = i >> 6;
        int c = i & 63;
        float p0 = pbuf[c * 100 + v];
        float p1 = pbuf[c * 100 + 25 + v];
        float p2 = pbuf[c * 100 + 50 + v];
        float p3 = pbuf[c * 100 + 75 + v];
        uv4[v * 64 + c] = make_float4(p1 - p0, p2 - p0, p2 - p1, p3 - p2);
        size_t m = ((size_t)(b * 25 + v)) * NSEG + s;
        feat[m * KD2 + c] = (_Float16)(p3 - p0);             // lvl1
        feat[m * KD2 + 2080 + c] = (_Float16)p0;             // start
    }
    __syncthreads();

    // levy: 2016 upper-triangle pairs, threads over k (coalesced 2B stores), v inner
    for (int ch = 0; ch < 8; ch++) {
        int pidx = ch * 256 + tid;
        if (pidx < 2016) {
            float disc = 16129.0f - 8.0f * (float)pidx;      // (127-2i)^2 at row starts
            int i = (int)((127.0f - sqrtf(disc)) * 0.5f);
            int off = 63 * i - (i * (i - 1)) / 2;
            while (off > pidx) { i--; off = 63 * i - (i * (i - 1)) / 2; }
            while (63 * (i + 1) - ((i + 1) * i) / 2 <= pidx) { i++; off = 63 * i - (i * (i - 1)) / 2; }
            int j = pidx - off + i + 1;
            int k = 64 + pidx;
            for (int v = 0; v < 25; v++) {
                float4 a = uv4[v * 64 + i];
                float4 bb = uv4[v * 64 + j];
                float val = 0.5f * (a.x * bb.z - bb.x * a.z + a.y * bb.w - bb.y * a.w);
                size_t m = ((size_t)(b * 25 + v)) * NSEG + s;
                feat[m * KD2 + k] = (_Float16)val;
            }
        }
    }
}

// ---------------- GEMM: xproj2[s][q][gate] = feat @ W_ih^T + bias (fp16 out) ------------
// BM=128, BN=128, BK=64; grid 640, r6's bid&7 XCD-residue mapping (FETCH 52 MB measured).
// NEW: 2 waves/block, wave tile 64x128 (af[4] x bf[8], acc[4][8]) -> LDS reads per kt
// drop 64->48 KB for the same 128 MFMA (LDS-BW-bound ceiling lifts ~45%->~50%).
// 4 blocks/CU (33 KB LDS), 8 waves/CU.
__global__ __launch_bounds__(128, 2) void gemm_kernel(const _Float16* __restrict__ feat,
                                                      const _Float16* __restrict__ wh,
                                                      const float* __restrict__ bias,
                                                      _Float16* __restrict__ xproj2) {
    int bid = blockIdx.x;
    int x = bid & 7;
    int t = bid >> 3;
    int nb = t & 3;
    int mt = (t >> 2) * 8 + x;
    if (mt >= 157) return;
    int m0 = mt * 128;
    int n0 = nb * 128;
    int tid = threadIdx.x;         // 0..127
    int wave = tid >> 6;           // 0..1
    int lane = tid & 63;
    int quad = lane >> 4;
    int l15 = lane & 15;
    int wm = wave * 64;

    int r8 = lane >> 3;                        // row within 8-row staging group
    int gcol = ((lane & 7) * 16) ^ (r8 * 16);  // XOR-swizzled source byte-col

    __shared__ __align__(16) _Float16 smem[16896];   // 33 KB (K-loop 32 KB; epilogue 128x132)
    char* As = (char*)smem;                    // 128 rows x 128 B
    char* Bs = (char*)smem + 128 * 128;        // 128 rows x 128 B

    const f32x4 z4 = {0.f, 0.f, 0.f, 0.f};
    f32x4 acc[4][8];
    for (int i = 0; i < 4; i++)
        for (int j = 0; j < 8; j++) acc[i][j] = z4;

    const char* featB = (const char*)feat;
    const char* whB = (const char*)wh;

    for (int kt = 0; kt < 34; kt++) {
        size_t kb = (size_t)kt * 128;
        __syncthreads();
        for (int it = 0; it < 8; it++) {       // 128 rows each of A and B, 2 waves
            int rb = it * 16 + wave * 8;
            g2lds16(featB + (size_t)(m0 + rb + r8) * KD2B + kb + gcol, As + rb * 128);
            g2lds16(whB + (size_t)(n0 + rb + r8) * KD2B + kb + gcol, Bs + rb * 128);
        }
        __syncthreads();

        for (int ks = 0; ks < 2; ks++) {
            int off = ((ks * 64) | (quad * 16)) ^ ((l15 & 7) * 16);
            f16x8 af[4], bf[8];
            for (int tt = 0; tt < 4; tt++)
                af[tt] = *(const f16x8*)(As + (wm + tt * 16 + l15) * 128 + off);
            for (int tt = 0; tt < 8; tt++)
                bf[tt] = *(const f16x8*)(Bs + (tt * 16 + l15) * 128 + off);
            for (int mtl = 0; mtl < 4; mtl++)
                for (int ntl = 0; ntl < 8; ntl++)
                    acc[mtl][ntl] = __builtin_amdgcn_mfma_f32_16x16x32_f16(af[mtl], bf[ntl], acc[mtl][ntl], 0, 0, 0);
        }
    }

    // epilogue: stage fp16 tile in LDS (row stride 132 halfwords -> conflict-free writes)
    __syncthreads();
    for (int ntl = 0; ntl < 8; ntl++) {
        int nl = ntl * 16 + l15;
        float bv = bias[n0 + nl];
        for (int mtl = 0; mtl < 4; mtl++)
            for (int r = 0; r < 4; r++) {
                int ml = wm + mtl * 16 + quad * 4 + r;
                smem[ml * 132 + nl] = (_Float16)(acc[mtl][ntl][r] + bv);
            }
    }
    __syncthreads();
    {
        int row = tid;             // 0..127
        int m = m0 + row;
        if (m < NROW) {
            unsigned q = (unsigned)m / 50u;
            unsigned s = (unsigned)m - q * 50u;
            const char* src = (const char*)smem + row * 264;
            char* dst = (char*)xproj2 + ((size_t)s * NSEQ + q) * 1024 + (size_t)n0 * 2;
            for (int i = 0; i < 16; i++)
                *(u32x4*)(dst + i * 16) = *(const u32x4*)(src + i * 16);
        }
    }
}

// ---------------- LSTM: 100 blocks x 4 seqs x 8 waves; NO per-step global ops -----------
// 25 steps of xproj preloaded into LDS (104 KB), refilled once at midpoint; all h
// outputs buffered in LDS (51 KB) and written out coalesced at the end. Steady-state
// step = LDS + MFMA + VALU + barrier only (no vmcnt drain on the critical path).
// Wave w owns hid [w*16,w*16+16) for all 4 gates; A rows replicated h[row&3]; quad=seq.
__global__ __launch_bounds__(512, 2) void lstm_kernel(const _Float16* __restrict__ xproj2,
                                                      const _Float16* __restrict__ whh,
                                                      _Float16* __restrict__ hseq) {
    int bid = blockIdx.x;        // 0..99
    int tid = threadIdx.x;
    int wave = tid >> 6;         // 0..7
    int lane = tid & 63;
    int quad = lane >> 4;        // = this lane's seq
    int col = lane & 15;
    int hid = wave * 16 + col;   // this lane's hid

    __shared__ __align__(16) char xbuf[25 * 4 * 1040];       // 104,000 B, rows padded
    __shared__ __align__(16) _Float16 hst[NSEG * 4 * HID];   // 51,200 B, [s][seq][hid]
    __shared__ __align__(16) _Float16 hbuf[2][4 * 144];      // 2,304 B, stride 144

    // B-frags: bfrag[g][kq]; B[k][n] = whh[g*128 + hid][k]
    f16x8 bfrag[4][4];
    for (int g = 0; g < 4; g++) {
        int n = g * 128 + hid;
        for (int kq = 0; kq < 4; kq++)
            bfrag[g][kq] = *(const f16x8*)(whh + (size_t)n * HID + kq * 32 + quad * 8);
    }
    for (int i = tid; i < 2 * 4 * 144; i += 512) ((_Float16*)hbuf)[i] = (_Float16)0.0f;
    float cst = 0.0f;

    const char* xsrc = (const char*)xproj2;
    // preload steps 0..24 (100 rows of 1 KB), 12-13 g2lds per wave
    for (int r = wave; r < 100; r += 8)
        g2lds16(xsrc + ((size_t)((r >> 2) * NSEQ + bid * 4 + (r & 3))) * 1024 + lane * 16,
                xbuf + r * 1040);
    __syncthreads();

    const f32x4 z4 = {0.f, 0.f, 0.f, 0.f};
    for (int half = 0; half < 2; half++) {
        for (int ss = 0; ss < 25; ss++) {
            int s = half * 25 + ss;
            int cur = s & 1;
            int nxt = cur ^ 1;

            // A-frags: A[m][k] = h[m&3][k] (replicated rows)
            f16x8 afrag[4];
            for (int kq = 0; kq < 4; kq++)
                afrag[kq] = *(const f16x8*)(&hbuf[cur][(col & 3) * 144 + kq * 32 + quad * 8]);

            // x_proj gates from LDS: 4 scalar reads for (seq=quad, hid)
            float xp[4];
            for (int g = 0; g < 4; g++)
                xp[g] = (float)(*(const _Float16*)(xbuf + (ss * 4 + quad) * 1040 +
                               (g * 128 + hid) * 2));

            f32x4 acc[4];
            for (int g = 0; g < 4; g++) {
                acc[g] = z4;
                for (int kq = 0; kq < 4; kq++)
                    acc[g] = __builtin_amdgcn_mfma_f32_16x16x32_f16(afrag[kq], bfrag[g][kq], acc[g], 0, 0, 0);
            }

            // extract element [quad] of each gate vector (C row quad*4+r = seq r)
            float gv[4];
            for (int g = 0; g < 4; g++) {
                float lo = (quad & 1) ? acc[g][1] : acc[g][0];
                float hi = (quad & 1) ? acc[g][3] : acc[g][2];
                gv[g] = (quad & 2) ? hi : lo;
            }

            float ip = gv[0] + xp[0];
            float fp = gv[1] + xp[1];
            float gp = gv[2] + xp[2];
            float op = gv[3] + xp[3];
            float si = __fdividef(1.0f, 1.0f + __expf(-ip));
            float sf = __fdividef(1.0f, 1.0f + __expf(-fp));
            float so = __fdividef(1.0f, 1.0f + __expf(-op));
            float eg = __expf(-2.0f * gp);
            float tg = __fdividef(1.0f - eg, 1.0f + eg);
            cst = sf * cst + si * tg;
            float ec = __expf(-2.0f * cst);
            float tc = __fdividef(1.0f - ec, 1.0f + ec);
            float hv = so * tc;
            _Float16 hv16 = (_Float16)hv;
            hbuf[nxt][quad * 144 + hid] = hv16;
            hst[(s * 4 + quad) * 128 + hid] = hv16;
            __syncthreads();
        }
        if (half == 0) {
            // refill slots 0..24 with steps 25..49 (one-time vmcnt drain)
            for (int r = wave; r < 100; r += 8)
                g2lds16(xsrc + ((size_t)((25 + (r >> 2)) * NSEQ + bid * 4 + (r & 3))) * 1024 + lane * 16,
                        xbuf + r * 1040);
            __syncthreads();
        }
    }

    // coalesced writeout of all 50 steps: 3200 dwordx4
    const u32x4* src = (const u32x4*)hst;
    for (int i = tid; i < 3200; i += 512) {
        int s = i >> 6;            // 64 vec4 per step
        int rem = i & 63;
        int seq = rem >> 4;
        int seg = rem & 15;
        u32x4 v = src[i];
        *(u32x4*)((char*)hseq + ((size_t)(s * NSEQ + bid * 4 + seq)) * 256 + seg * 16) = v;
    }
}

// ---------------- transpose: out[b][hid][s][v] = hseq[s][b*25+v][hid] -------------------
__global__ __launch_bounds__(256) void tr_kernel(const _Float16* __restrict__ hseq,
                                                 float* __restrict__ out) {
    int bid = blockIdx.x;        // 0..799 = b*50+s
    int b = bid / NSEG;
    int s = bid - b * NSEG;
    int tid = threadIdx.x;

    __shared__ _Float16 buf[25 * 130];   // [v][hid], padded 128->130

    const uint32_t* src32 = (const uint32_t*)(hseq + ((size_t)s * NSEQ + b * 25) * HID);
    uint32_t* buf32 = (uint32_t*)buf;
    for (int i = tid; i < 1600; i += 256) {       // 25 rows x 64 dwords, contiguous read
        int v = i >> 6;
        int d = i & 63;
        buf32[v * 65 + d] = src32[i];
    }
    __syncthreads();
    for (int i = tid; i < 3200; i += 256) {
        int hid = i / 25;
        int v = i - hid * 25;
        out[(((size_t)b * 128 + hid) * NSEG + s) * 25 + v] = (float)buf[v * 130 + hid];
    }
}

extern "C" void kernel_launch(void* const* d_in, const int* in_sizes, int n_in,
                              void* d_out, int out_size, void* d_ws, size_t ws_size,
                              hipStream_t stream) {
    const float* x = (const float*)d_in[0];
    const float* Wih = (const float*)d_in[1];
    const float* Whh = (const float*)d_in[2];
    const float* bih = (const float*)d_in[3];
    const float* bhh = (const float*)d_in[4];
    float* out = (float*)d_out;

    char* ws = (char*)d_ws;
    size_t off = 0;
    _Float16* feat = (_Float16*)(ws + off);   off += (size_t)NROW_PAD * KD2 * 2;      // 87.5 MB
    _Float16* xproj2 = (_Float16*)(ws + off); off += (size_t)NSEG * NSEQ * GATES * 2; // 20.5 MB
    _Float16* hseq = (_Float16*)(ws + off);   off += (size_t)NSEG * NSEQ * HID * 2;   // 5.1 MB
    _Float16* wh = (_Float16*)(ws + off);     off += (size_t)512 * KD2 * 2;           // 2.2 MB
    _Float16* whh16 = (_Float16*)(ws + off);  off += (size_t)512 * HID * 2;
    float* bias = (float*)(ws + off);         off += 512 * 4;

    hipLaunchKernelGGL(feat_kernel, dim3(864), dim3(256), 0, stream,
                       x, Wih, Whh, bih, bhh, feat, wh, whh16, bias);
    hipLaunchKernelGGL(gemm_kernel, dim3(640), dim3(128), 0, stream, feat, wh, bias, xproj2);
    hipLaunchKernelGGL(lstm_kernel, dim3(100), dim3(512), 0, stream, xproj2, whh16, hseq);
    hipLaunchKernelGGL(tr_kernel, dim3(16 * NSEG), dim3(256), 0, stream, hseq, out);
}